// Round 4
// baseline (192.617 us; speedup 1.0000x reference)
//
#include <hip/hip_runtime.h>
#include <math.h>

// ---------- problem constants ----------
#define BATCH   16
#define LIN     320000
#define LP      322048          // LIN + 2048 (reflect pad 1024 each side)
#define HLP     (LP/2)          // 161024 : even/odd de-interleaved length
#define TFR     626             // frames per batch
#define MTOT    (BATCH*TFR)     // 10016
#define KD2     1024            // radix-2 GEMM K (length-1024 sub-DFTs)
#define KOUT    1025
#define IMAG_OFF ((long)MTOT*KOUT)   // 10266400

// radix-2 packed columns: C = g*64 + q*16 + u ; k' = g*16+u (0..543, valid<=512)
// q: 0=E_r 1=E_i 2=O_r 3=O_i.  S[k'] = E + tw*O ; S[1024-k'] = conj(E - tw*O)
#define MT 79                   // m-tiles (128 rows)
#define NT 17                   // k'-tiles (32 k' = 128 packed cols)
// band-per-XCD mapping: XCD j owns mt in [10j, 10j+10) (last band 9 + 17 dead wgs)
#define BAND 10
#define GEMM_GRID (8*BAND*NT)   // 1360

#define XP_BLOCKS   ((BATCH*LP)/2048)   // 2516 (8 elems/thread)
#define W2_BLOCKS   (34*16)             // 544: 34 k'-groups x 16 j-blocks

typedef __attribute__((ext_vector_type(8))) short short8;
typedef __attribute__((ext_vector_type(4))) short short4v;
typedef __attribute__((ext_vector_type(4))) float float4v;
typedef unsigned short ushort_t;

#define PI_OVER_1024 0.0030679615757712823f

static __device__ __forceinline__ ushort_t f32_to_bf16(float f) {
    union { float f; unsigned u; } un; un.f = f;
    unsigned r = un.u + 0x7fffu + ((un.u >> 16) & 1u);   // RNE
    return (ushort_t)(r >> 16);
}

static __device__ __forceinline__ void async_copy16(const void* g, void* l) {
    __builtin_amdgcn_global_load_lds(
        (const __attribute__((address_space(1))) void*)g,
        (__attribute__((address_space(3))) void*)l, 16, 0, 0);
}

// ---------- prep A: reflect-pad fp32 x -> bf16 even/odd de-interleaved ----------
__global__ void prep_x(const float* __restrict__ x,
                       ushort_t* __restrict__ xpe,
                       ushort_t* __restrict__ xpo) {
    int i0 = blockIdx.x * 2048 + threadIdx.x * 8;   // multiple of 8; never spans batch
    int b  = i0 / LP;
    int p0 = i0 - b * LP;                    // even
    float v[8];
    if (p0 >= 1024 && p0 + 8 <= 1024 + LIN) {        // interior fast path
        const float* src = x + b * LIN + (p0 - 1024);
        float4v u0 = *(const float4v*)src;
        float4v u1 = *(const float4v*)(src + 4);
#pragma unroll
        for (int e = 0; e < 4; ++e) { v[e] = u0[e]; v[4+e] = u1[e]; }
    } else {
#pragma unroll
        for (int e = 0; e < 8; ++e) {
            int i = i0 + e;
            int bb = i / LP;
            int j = (i - bb * LP) - 1024;
            if (j < 0) j = -j;
            else if (j >= LIN) j = 2 * LIN - 2 - j;
            v[e] = x[bb * LIN + j];
        }
    }
    short4v ve, vo;
#pragma unroll
    for (int e = 0; e < 4; ++e) {
        ve[e] = (short)f32_to_bf16(v[2*e]);
        vo[e] = (short)f32_to_bf16(v[2*e+1]);
    }
    int he = b * HLP + (p0 >> 1);
    *(short4v*)(xpe + he) = ve;
    *(short4v*)(xpo + he) = vo;
}

// ---------- prep B: packed radix-2 weight build ----------
// row C = gk*64 + q*16 + u, cols j (K=1024)
// WE_r[j,k']=wr[2j,k']  WE_i=wi[2j,k']
// WO_r[j,k']=cosd*wr[2j+1,k']-sind*wi[2j+1,k']   (d = pi*k'/1024)
// WO_i[j,k']=cosd*wi[2j+1,k']+sind*wr[2j+1,k']
__global__ void prep_w(const float* __restrict__ wr,
                       const float* __restrict__ wi,
                       ushort_t* __restrict__ wbt) {
    __shared__ float sR[128][17];
    __shared__ float sI[128][17];
    int w  = blockIdx.x;          // 0..543
    int gk = w >> 4;              // k'-group 0..33
    int j0 = (w & 15) * 64;       // j-block
    int n0 = j0 * 2;              // source rows n0..n0+127 (<=2047)
    int kb = gk * 16;             // k' base (<=528; reads <=543 < 1025 OK)
    {
        int c  = threadIdx.x & 15;
        int rs = threadIdx.x >> 4;
#pragma unroll
        for (int it = 0; it < 8; ++it) {
            int row = rs + it * 16;
            long src = (long)(n0 + row) * KOUT + kb + c;
            sR[row][c] = wr[src];
            sI[row][c] = wi[src];
        }
    }
    __syncthreads();
    int q  = threadIdx.x >> 6;    // wave = quantity (uniform branch)
    int jj = threadIdx.x & 63;
#pragma unroll
    for (int u = 0; u < 16; ++u) {
        int kp = kb + u;
        float val;
        if (q == 0)      val = sR[2*jj][u];
        else if (q == 1) val = sI[2*jj][u];
        else {
            float r1 = sR[2*jj+1][u], i1 = sI[2*jj+1][u];
            float a  = (float)kp * PI_OVER_1024;
            float sd = __sinf(a), cd = __cosf(a);
            val = (q == 2) ? (cd * r1 - sd * i1) : (cd * i1 + sd * r1);
        }
        if (kp > 512) val = 0.f;                 // pad cols -> exact zero acc
        wbt[(long)(gk * 64 + q * 16 + u) * KD2 + j0 + jj] = f32_to_bf16(val);
    }
}

// ---------- main GEMM: radix-2, 128x128 tile, BK=32, double-buffered prefetch ----
// T3-minimum 2-phase: STAGE(next) issued BEFORE compute(cur); one barrier/iter.
// LDS 2 bufs x 3 tiles x 8 KB = 48 KB -> 3 blocks/CU.
// XCD band mapping unchanged (R3: FETCH 34 MB, ~demand minimum).
__global__ __launch_bounds__(256) void stft_gemm(const ushort_t* __restrict__ xpe,
                                                 const ushort_t* __restrict__ xpo,
                                                 const ushort_t* __restrict__ wbt,
                                                 float* __restrict__ out) {
    __shared__ __align__(16) ushort_t lds[2][3][128 * 32];   // 48 KB

    const int tid = threadIdx.x;
    const int f   = blockIdx.x;            // 0..1359
    const int xcd = f & 7;                 // HW round-robins blocks across XCDs
    const int ii  = f >> 3;                // 0..169
    const int mt  = xcd * BAND + (ii % BAND);
    const int nt  = ii / BAND;             // 0..16
    if (mt >= MT) return;                  // 17 dead wgs (whole block exits)
    const int m0  = mt * 128;
    const int c0  = nt * 128;              // packed col base

    // staging source offsets: slot s=j*256+tid -> row=s>>2, phys granule=s&3,
    // logical granule g=(s&3)^sw(row), sw(row)=(row&3)^((row>>2)&3); src k-off=g*8
    int baseA[2], baseB[2];
#pragma unroll
    for (int j = 0; j < 2; ++j) {
        int slot = j * 256 + tid;
        int row  = slot >> 2;
        int g    = (slot & 3) ^ ((row & 3) ^ ((row >> 2) & 3));
        int m = m0 + row; if (m > MTOT - 1) m = MTOT - 1;   // clamp; stores guarded
        int b = m / TFR;
        int t = m - b * TFR;
        baseA[j] = b * HLP + t * 256 + g * 8;   // frame step = 256 in e/o streams
        baseB[j] = (c0 + row) * KD2 + g * 8;    // c0+row < 2176 always
    }

    const int wave = tid >> 6;
    const int lane = tid & 63;
    const int wm = (wave >> 1) * 64;
    const int wn = (wave & 1) * 64;
    const int lm = lane & 15;
    const int quad = lane >> 4;

    // hoisted ds_read offsets (ushort units); only buffer base varies per iter
    int aoff[4], boff[4];
#pragma unroll
    for (int i = 0; i < 4; ++i) {
        int ra = wm + i * 16 + lm;
        aoff[i] = ra * 32 + ((quad ^ ((ra & 3) ^ ((ra >> 2) & 3))) * 8);
        int rb = wn + i * 16 + lm;
        boff[i] = rb * 32 + ((quad ^ ((rb & 3) ^ ((rb >> 2) & 3))) * 8);
    }

    float4v acc[4][4];
#pragma unroll
    for (int mi = 0; mi < 4; ++mi)
#pragma unroll
        for (int ni = 0; ni < 4; ++ni)
            acc[mi][ni] = (float4v){0.f, 0.f, 0.f, 0.f};

#define STAGE(bufi, kk0)                                                          \
    do {                                                                          \
        char* D_ = (char*)&lds[bufi][0][0];                                       \
        _Pragma("unroll")                                                         \
        for (int j = 0; j < 2; ++j) {                                             \
            int ds_ = (j * 256 + tid) * 16;                                       \
            async_copy16(xpe + baseA[j] + (kk0), D_ + ds_);                       \
            async_copy16(xpo + baseA[j] + (kk0), D_ + 8192 + ds_);                \
            async_copy16(wbt + baseB[j] + (kk0), D_ + 16384 + ds_);               \
        }                                                                         \
    } while (0)

    // prologue: stage first tile, drain
    STAGE(0, 0);
    __syncthreads();

#pragma unroll 2
    for (int t = 0; t < 32; ++t) {
        const int buf = t & 1;
        if (t < 31) STAGE(buf ^ 1, (t + 1) * 32);   // prefetch next (hidden under MFMA)

        const ushort_t* L = &lds[buf][0][0];
        short8 ae[4], ao[4], bfr[4];
#pragma unroll
        for (int mi = 0; mi < 4; ++mi) {
            ae[mi] = *(const short8*)(L + aoff[mi]);
            ao[mi] = *(const short8*)(L + 4096 + aoff[mi]);
        }
#pragma unroll
        for (int ni = 0; ni < 4; ++ni)
            bfr[ni] = *(const short8*)(L + 8192 + boff[ni]);
#pragma unroll
        for (int mi = 0; mi < 4; ++mi)
#pragma unroll
            for (int ni = 0; ni < 4; ++ni)
                acc[mi][ni] = __builtin_amdgcn_mfma_f32_16x16x32_bf16(
                    (ni < 2) ? ae[mi] : ao[mi], bfr[ni], acc[mi][ni], 0, 0, 0);

        __syncthreads();   // drains vmcnt (prefetch landed) + lgkm; next iter safe
    }
#undef STAGE

    // epilogue: lane holds E_r,E_i,O_r,O_i of its k' in acc[mi][0..3][rg].
    // butterfly: P = tw*O, tw = e^{-i pi k'/1024};
    //   out[k']      = (E_r+P_r, E_i+P_i)
    //   out[1024-k'] = (E_r-P_r, -E_i+P_i)   (k'=512: O-imag weights exactly 0 -> identical)
    const int grp = (c0 + wn) >> 6;
    const int kp  = grp * 16 + lm;             // this lane's k'
    if (kp <= 512) {
        float a  = (float)kp * PI_OVER_1024;
        float sd = __sinf(a), cd = __cosf(a);  // tw = cd - i*sd
#pragma unroll
        for (int mi = 0; mi < 4; ++mi) {
#pragma unroll
            for (int rg = 0; rg < 4; ++rg) {
                int m = m0 + wm + mi * 16 + quad * 4 + rg;
                if (m < MTOT) {
                    float Er = acc[mi][0][rg], Ei = acc[mi][1][rg];
                    float Or = acc[mi][2][rg], Oi = acc[mi][3][rg];
                    float Pr = cd * Or + sd * Oi;
                    float Pi = cd * Oi - sd * Or;
                    long rb = (long)m * KOUT;
                    out[rb + kp]                   = Er + Pr;
                    out[IMAG_OFF + rb + kp]        = Ei + Pi;
                    out[rb + 1024 - kp]            = Er - Pr;
                    out[IMAG_OFF + rb + 1024 - kp] = -Ei + Pi;
                }
            }
        }
    }
}

extern "C" void kernel_launch(void* const* d_in, const int* in_sizes, int n_in,
                              void* d_out, int out_size, void* d_ws, size_t ws_size,
                              hipStream_t stream) {
    const float* x  = (const float*)d_in[0];     // fp32 (16, 320000)
    const float* wr = (const float*)d_in[1];     // fp32 (2048, 1025)
    const float* wi = (const float*)d_in[2];     // fp32 (2048, 1025)
    float* out = (float*)d_out;                  // fp32, 2*16*626*1025

    ushort_t* xpe = (ushort_t*)d_ws;             // 16*161024 bf16 = 5.15 MB
    ushort_t* xpo = xpe + BATCH * HLP;           // 5.15 MB
    ushort_t* wbt = xpo + BATCH * HLP;           // 2176*1024 bf16 = 4.46 MB

    prep_x<<<XP_BLOCKS, 256, 0, stream>>>(x, xpe, xpo);
    prep_w<<<W2_BLOCKS, 256, 0, stream>>>(wr, wi, wbt);
    stft_gemm<<<GEMM_GRID, 256, 0, stream>>>(xpe, xpo, wbt, out);   // band-mapped
}

// Round 5
// 172.831 us; speedup vs baseline: 1.1145x; 1.1145x over previous
//
#include <hip/hip_runtime.h>
#include <math.h>

// ---------- problem constants ----------
#define BATCH   16
#define LIN     320000
#define LP      322048          // LIN + 2048 (reflect pad 1024 each side)
#define HLP     (LP/2)          // 161024 : even/odd de-interleaved length
#define TFR     626             // frames per batch
#define MTOT    (BATCH*TFR)     // 10016
#define KD2     1024            // radix-2 GEMM K (length-1024 sub-DFTs)
#define KOUT    1025
#define IMAG_OFF ((long)MTOT*KOUT)   // 10266400

// radix-2 packed columns: C = g*64 + q*16 + u ; k' = g*16+u (0..575, valid<=512)
// q: 0=E_r 1=E_i 2=O_r 3=O_i.  S[k'] = E + tw*O ; S[1024-k'] = conj(E - tw*O)
#define MT 79                   // m-tiles (128 rows)
#define NT 9                    // k'-tiles (64 k' = 256 packed cols)
#define WROWS 2304              // 9*256 packed weight rows (k' padded to 576)
// band-per-XCD mapping: XCD j owns mt in [10j, 10j+10) (last band 9 + 9 dead wgs)
#define BAND 10
#define GEMM_GRID (8*BAND*NT)   // 720

#define XP_BLOCKS   ((BATCH*LP)/2048)   // 2516 (8 elems/thread)
#define W2_BLOCKS   (36*16)             // 576: 36 k'-groups x 16 j-blocks

typedef __attribute__((ext_vector_type(8))) short short8;
typedef __attribute__((ext_vector_type(4))) short short4v;
typedef __attribute__((ext_vector_type(4))) float float4v;
typedef unsigned short ushort_t;

#define PI_OVER_1024 0.0030679615757712823f

static __device__ __forceinline__ ushort_t f32_to_bf16(float f) {
    union { float f; unsigned u; } un; un.f = f;
    unsigned r = un.u + 0x7fffu + ((un.u >> 16) & 1u);   // RNE
    return (ushort_t)(r >> 16);
}

static __device__ __forceinline__ void async_copy16(const void* g, void* l) {
    __builtin_amdgcn_global_load_lds(
        (const __attribute__((address_space(1))) void*)g,
        (__attribute__((address_space(3))) void*)l, 16, 0, 0);
}

// ---------- prep A: reflect-pad fp32 x -> bf16 even/odd de-interleaved ----------
__global__ void prep_x(const float* __restrict__ x,
                       ushort_t* __restrict__ xpe,
                       ushort_t* __restrict__ xpo) {
    int i0 = blockIdx.x * 2048 + threadIdx.x * 8;   // multiple of 8; never spans batch
    int b  = i0 / LP;
    int p0 = i0 - b * LP;                    // even
    float v[8];
    if (p0 >= 1024 && p0 + 8 <= 1024 + LIN) {        // interior fast path
        const float* src = x + b * LIN + (p0 - 1024);
        float4v u0 = *(const float4v*)src;
        float4v u1 = *(const float4v*)(src + 4);
#pragma unroll
        for (int e = 0; e < 4; ++e) { v[e] = u0[e]; v[4+e] = u1[e]; }
    } else {
#pragma unroll
        for (int e = 0; e < 8; ++e) {
            int i = i0 + e;
            int bb = i / LP;
            int j = (i - bb * LP) - 1024;
            if (j < 0) j = -j;
            else if (j >= LIN) j = 2 * LIN - 2 - j;
            v[e] = x[bb * LIN + j];
        }
    }
    short4v ve, vo;
#pragma unroll
    for (int e = 0; e < 4; ++e) {
        ve[e] = (short)f32_to_bf16(v[2*e]);
        vo[e] = (short)f32_to_bf16(v[2*e+1]);
    }
    int he = b * HLP + (p0 >> 1);
    *(short4v*)(xpe + he) = ve;
    *(short4v*)(xpo + he) = vo;
}

// ---------- prep B: packed radix-2 weight build ----------
// row C = gk*64 + q*16 + u, cols j (K=1024)
// WE_r[j,k']=wr[2j,k']  WE_i=wi[2j,k']
// WO_r[j,k']=cosd*wr[2j+1,k']-sind*wi[2j+1,k']   (d = pi*k'/1024)
// WO_i[j,k']=cosd*wi[2j+1,k']+sind*wr[2j+1,k']
__global__ void prep_w(const float* __restrict__ wr,
                       const float* __restrict__ wi,
                       ushort_t* __restrict__ wbt) {
    __shared__ float sR[128][17];
    __shared__ float sI[128][17];
    int w  = blockIdx.x;          // 0..575
    int gk = w >> 4;              // k'-group 0..35
    int j0 = (w & 15) * 64;       // j-block
    int n0 = j0 * 2;              // source rows n0..n0+127 (<=2047)
    int kb = gk * 16;             // k' base (<=560; reads <=575 < 1025 OK)
    {
        int c  = threadIdx.x & 15;
        int rs = threadIdx.x >> 4;
#pragma unroll
        for (int it = 0; it < 8; ++it) {
            int row = rs + it * 16;
            long src = (long)(n0 + row) * KOUT + kb + c;
            sR[row][c] = wr[src];
            sI[row][c] = wi[src];
        }
    }
    __syncthreads();
    int q  = threadIdx.x >> 6;    // wave = quantity (uniform branch)
    int jj = threadIdx.x & 63;
#pragma unroll
    for (int u = 0; u < 16; ++u) {
        int kp = kb + u;
        float val;
        if (q == 0)      val = sR[2*jj][u];
        else if (q == 1) val = sI[2*jj][u];
        else {
            float r1 = sR[2*jj+1][u], i1 = sI[2*jj+1][u];
            float a  = (float)kp * PI_OVER_1024;
            float sd = __sinf(a), cd = __cosf(a);
            val = (q == 2) ? (cd * r1 - sd * i1) : (cd * i1 + sd * r1);
        }
        if (kp > 512) val = 0.f;                 // pad cols -> exact zero acc
        wbt[(long)(gk * 64 + q * 16 + u) * KD2 + j0 + jj] = f32_to_bf16(val);
    }
}

// ---------- main GEMM: radix-2, 128m x 256c tile, BK=64, 8 waves ----------
// R3-proven structure (single buffer, 2 barriers/K-tile, 8-granule XOR swizzle:
// measured 0 bank conflicts) widened to BN=256: staging bytes/MFMA -33%,
// blocks 1343->711, occupancy 16 waves/CU.
// XCD band mapping: XCD j pinned to mt band [10j,10j+10); A band L2-resident.
__global__ __launch_bounds__(512, 4) void stft_gemm(const ushort_t* __restrict__ xpe,
                                                    const ushort_t* __restrict__ xpo,
                                                    const ushort_t* __restrict__ wbt,
                                                    float* __restrict__ out) {
    __shared__ __align__(16) ushort_t Ae[128 * 64];   // 16 KB
    __shared__ __align__(16) ushort_t Ao[128 * 64];   // 16 KB
    __shared__ __align__(16) ushort_t Bs[256 * 64];   // 32 KB

    const int tid = threadIdx.x;
    const int f   = blockIdx.x;            // 0..719
    const int xcd = f & 7;                 // HW round-robins blocks across XCDs
    const int ii  = f >> 3;                // 0..89
    const int mt  = xcd * BAND + (ii % BAND);
    const int nt  = ii / BAND;             // 0..8
    if (mt >= MT) return;                  // 9 dead wgs (whole block exits)
    const int m0  = mt * 128;
    const int c0  = nt * 256;              // packed col base (<=2048)

    // staging source offsets: slot s -> row=s>>3, phys granule=s&7,
    // logical granule g=(s&7)^(row&7); source k-offset = g*8
    int baseA[2], baseB[4];
#pragma unroll
    for (int j = 0; j < 2; ++j) {
        int slot = j * 512 + tid;          // 0..1023 (A: 128 rows x 8 granules)
        int row  = slot >> 3;
        int g    = (slot & 7) ^ (row & 7);
        int m = m0 + row; if (m > MTOT - 1) m = MTOT - 1;   // clamp; stores guarded
        int b = m / TFR;
        int t = m - b * TFR;
        baseA[j] = b * HLP + t * 256 + g * 8;   // frame step = 256 in e/o streams
    }
#pragma unroll
    for (int j = 0; j < 4; ++j) {
        int slot = j * 512 + tid;          // 0..2047 (B: 256 rows x 8 granules)
        int row  = slot >> 3;
        int g    = (slot & 7) ^ (row & 7);
        baseB[j] = (c0 + row) * KD2 + g * 8;    // c0+row < 2304 always
    }

    const int wave = tid >> 6;             // 0..7
    const int lane = tid & 63;
    const int wm = (wave >> 2) * 64;       // 2 m-rows of waves
    const int wn = (wave & 3) * 64;        // 4 n-cols of waves
    const int lm = lane & 15;
    const int quad = lane >> 4;

    float4v acc[4][4];
#pragma unroll
    for (int mi = 0; mi < 4; ++mi)
#pragma unroll
        for (int ni = 0; ni < 4; ++ni)
            acc[mi][ni] = (float4v){0.f, 0.f, 0.f, 0.f};

    for (int k0 = 0; k0 < KD2; k0 += 64) {
        __syncthreads();                          // prior ds_reads done
#pragma unroll
        for (int j = 0; j < 2; ++j) {
            int ds = (j * 512 + tid) * 16;
            async_copy16(xpe + baseA[j] + k0, (char*)Ae + ds);
            async_copy16(xpo + baseA[j] + k0, (char*)Ao + ds);
        }
#pragma unroll
        for (int j = 0; j < 4; ++j)
            async_copy16(wbt + baseB[j] + k0, (char*)Bs + (j * 512 + tid) * 16);
        __syncthreads();                          // drains vmcnt

#pragma unroll
        for (int kk = 0; kk < 2; ++kk) {
            short8 ae[4], ao[4], bfr[4];
#pragma unroll
            for (int mi = 0; mi < 4; ++mi) {
                int row = wm + mi * 16 + lm;
                int pg  = (kk * 4 + quad) ^ (row & 7);
                ae[mi] = *(const short8*)&Ae[row * 64 + pg * 8];
                ao[mi] = *(const short8*)&Ao[row * 64 + pg * 8];
            }
#pragma unroll
            for (int ni = 0; ni < 4; ++ni) {
                int row = wn + ni * 16 + lm;
                int pg  = (kk * 4 + quad) ^ (row & 7);
                bfr[ni] = *(const short8*)&Bs[row * 64 + pg * 8];
            }
#pragma unroll
            for (int mi = 0; mi < 4; ++mi)
#pragma unroll
                for (int ni = 0; ni < 4; ++ni)
                    acc[mi][ni] = __builtin_amdgcn_mfma_f32_16x16x32_bf16(
                        (ni < 2) ? ae[mi] : ao[mi], bfr[ni], acc[mi][ni], 0, 0, 0);
        }
    }

    // epilogue: lane holds E_r,E_i,O_r,O_i of its k' in acc[mi][0..3][rg].
    // butterfly: P = tw*O, tw = e^{-i pi k'/1024};
    //   out[k']      = (E_r+P_r, E_i+P_i)
    //   out[1024-k'] = (E_r-P_r, -E_i+P_i)   (k'=512: O-imag weights exactly 0 -> identical)
    const int grp = (c0 + wn) >> 6;
    const int kp  = grp * 16 + lm;             // this lane's k'
    if (kp <= 512) {
        float a  = (float)kp * PI_OVER_1024;
        float sd = __sinf(a), cd = __cosf(a);  // tw = cd - i*sd
#pragma unroll
        for (int mi = 0; mi < 4; ++mi) {
#pragma unroll
            for (int rg = 0; rg < 4; ++rg) {
                int m = m0 + wm + mi * 16 + quad * 4 + rg;
                if (m < MTOT) {
                    float Er = acc[mi][0][rg], Ei = acc[mi][1][rg];
                    float Or = acc[mi][2][rg], Oi = acc[mi][3][rg];
                    float Pr = cd * Or + sd * Oi;
                    float Pi = cd * Oi - sd * Or;
                    long rb = (long)m * KOUT;
                    out[rb + kp]                   = Er + Pr;
                    out[IMAG_OFF + rb + kp]        = Ei + Pi;
                    out[rb + 1024 - kp]            = Er - Pr;
                    out[IMAG_OFF + rb + 1024 - kp] = -Ei + Pi;
                }
            }
        }
    }
}

extern "C" void kernel_launch(void* const* d_in, const int* in_sizes, int n_in,
                              void* d_out, int out_size, void* d_ws, size_t ws_size,
                              hipStream_t stream) {
    const float* x  = (const float*)d_in[0];     // fp32 (16, 320000)
    const float* wr = (const float*)d_in[1];     // fp32 (2048, 1025)
    const float* wi = (const float*)d_in[2];     // fp32 (2048, 1025)
    float* out = (float*)d_out;                  // fp32, 2*16*626*1025

    ushort_t* xpe = (ushort_t*)d_ws;             // 16*161024 bf16 = 5.15 MB
    ushort_t* xpo = xpe + BATCH * HLP;           // 5.15 MB
    ushort_t* wbt = xpo + BATCH * HLP;           // 2304*1024 bf16 = 4.72 MB

    prep_x<<<XP_BLOCKS, 256, 0, stream>>>(x, xpe, xpo);
    prep_w<<<W2_BLOCKS, 256, 0, stream>>>(wr, wi, wbt);
    stft_gemm<<<GEMM_GRID, 512, 0, stream>>>(xpe, xpo, wbt, out);   // band-mapped
}